// Round 8
// baseline (158.074 us; speedup 1.0000x reference)
//
#include <hip/hip_runtime.h>

// B=8, Cin=64, H=W=128, Cout=64, 9 bilinear taps at (i+0.4, j+0.4) == exact 4x4
// conv with zero pad. Implicit GEMM, bf16 MFMA 16x16x32.
//
// v11: 2-row strips -> halve the wb2 L2 stream (the real bottleneck).
//   - v10 post-mortem: conv is L2-BW-bound: 8 blk/CU x (66 KB x + 128 KB wb2
//     + 16 KB out) ~= 1.7 MB/CU @ ~134 GB/s/CU ~= observed ~15 us. wb2 re-read
//     per 64px-row strip is 60% of all L2 traffic.
//   - v11: strip = 2 out rows x 64 px, SINGLE wave, barrier-free (v10 ring).
//     Two adjacent out rows share IDENTICAL A-fragments per staged input row
//     (only the B tap-row differs: out0 uses r, out1 uses r-1) -> afr loaded
//     once, wb2 read once per 2 rows. 10 phases = 2 passes x 5 rows.
//   - acc0+acc1 = 128 VGPRs; depth-1 pipeline WRITE(k)|LOAD(k+1)|COMPUTE(k)
//     (single GM buffer) keeps VGPR ~230 < 256 cap. 1024 blocks x 64 thr.
//   - Same (p, rs=0..15, mi, nn) accumulation order per output element ->
//     bitwise-identical output.

#define CIN   64
#define COUT  64
#define HH    128
#define WW    128

typedef __attribute__((ext_vector_type(8))) short bf16x8;   // 8 bf16 = 4 VGPRs
typedef __attribute__((ext_vector_type(4))) float f32x4;
typedef __attribute__((ext_vector_type(4))) unsigned int u32x4;

__device__ __forceinline__ unsigned short f2bf(float f) {
  unsigned int u = __float_as_uint(f);
  u = (u + 0x7fffu + ((u >> 16) & 1u)) >> 16;   // RNE
  return (unsigned short)u;
}

__device__ __forceinline__ unsigned int cvtpk(float lo, float hi) {
  unsigned int r;                                // D = {bf16(lo), bf16(hi)} RNE
  asm("v_cvt_pk_bf16_f32 %0, %1, %2" : "=v"(r) : "v"(lo), "v"(hi));
  return r;
}

// ---------------------------------------------------------------------------
// W4[o][c][r][s] = sum_k w[o,c,k] * cy_k(r-iy_k) * cx_k(s-ix_k).
// Stream layout: wb2[(((p*16+rs)*4 + n)*64 + lane)*8 + j]; consuming lane l
// holds o = n*16 + (l&15), ch = p*32 + (l>>4)*8 + j, for tap rs. (verified)
// ---------------------------------------------------------------------------
__global__ void make_wb(const float* __restrict__ wgt,
                        const float* __restrict__ off,
                        unsigned short* __restrict__ wb2)
{
  int id = blockIdx.x * 64 + threadIdx.x;       // 4096 = 64*64
  int o = id >> 6, c = id & 63;
  float W16[16];
  #pragma unroll
  for (int i = 0; i < 16; ++i) W16[i] = 0.f;
  for (int k = 0; k < 9; ++k) {
    float dy = off[2*k], dx = off[2*k+1];
    float fyf = floorf(dy), fxf = floorf(dx);
    int   iy = (int)fyf,   ix = (int)fxf;       // in {0,1,2}
    float fy = dy - fyf,   fx = dx - fxf;
    float wk = wgt[(o*CIN + c)*9 + k];
    W16[(iy  )*4 + ix  ] += wk * (1.f-fy)*(1.f-fx);
    W16[(iy  )*4 + ix+1] += wk * (1.f-fy)*fx;
    W16[(iy+1)*4 + ix  ] += wk * fy*(1.f-fx);
    W16[(iy+1)*4 + ix+1] += wk * fy*fx;
  }
  int p = c >> 5, q = (c >> 3) & 3, j = c & 7;
  int n = o >> 4, m15 = o & 15;
  int lanei = q*16 + m15;
  for (int rs = 0; rs < 16; ++rs)
    wb2[(size_t)(((p*16 + rs)*4 + n)*64 + lanei)*8 + j] = f2bf(W16[rs]);
}

// ---------------------------------------------------------------------------
// conv: 1 wave per block, strip = 2 out rows x 64 px x 64 Cout, no barriers.
// LDS ring: slot(k&1) = 68 cols x 4 chunk-slots x 16 B = 4352 B, XOR swizzle.
// ---------------------------------------------------------------------------
__global__ __launch_bounds__(64, 2)   // VGPR cap 256
void conv_mfma(const float* __restrict__ x,
               const unsigned short* __restrict__ wb2,
               float* __restrict__ out)
{
  __shared__ __align__(16) char lds[17408];     // ring 2x4352 B; epi f32[64][68]

  const int wg  = blockIdx.x;                   // 1024
  const int xcd = wg & 7;
  const int i   = wg >> 3;                      // 0..127
  const int b   = i >> 4;                       // 0..7
  const int r4  = i & 15;
  const int y0  = xcd * 16 + (r4 >> 1) * 2;     // first out row of the pair
  const int x0  = (r4 & 1) * 64;                // x half
  const int lane = threadIdx.x;                 // 0..63
  const int m15  = lane & 15;
  const int q    = lane >> 4;

  // ---- per-lane staging constants (same as v10) ----
  int gx   = x0 - 1 + lane;                     // main col = lane
  bool gxv = ((unsigned)gx < (unsigned)WW);
  int gxc  = gx < 0 ? 0 : (gx > WW-1 ? WW-1 : gx);
  const int he = (lane >> 4) < 3 ? (lane >> 4) : 2;   // halo col 64+he
  int gxh  = x0 + 63 + he;
  bool gxhv = ((unsigned)gxh < (unsigned)WW) && (lane < 48);
  int gxhc = gxh > WW-1 ? WW-1 : gxh;
  const int hp = lane & 15;                     // halo ch-pair: ch = 2hp, 2hp+1
  const int hoff = (64 + he)*64 + ((hp >> 2) & 3)*16 + (hp & 3)*4;

  int stoff[4];
  #pragma unroll
  for (int c = 0; c < 4; ++c)
    stoff[c] = lane*64 + ((c + (lane >> 2)) & 3)*16;

  int aoff[4];
  #pragma unroll
  for (int s = 0; s < 4; ++s) {
    int c0 = m15 + s;
    aoff[s] = c0*64 + ((q + (c0 >> 2)) & 3)*16;
  }

  f32x4 acc0[4][4], acc1[4][4];
  #pragma unroll
  for (int mi = 0; mi < 4; ++mi)
    #pragma unroll
    for (int nn = 0; nn < 4; ++nn) {
      acc0[mi][nn] = (f32x4){0.f, 0.f, 0.f, 0.f};
      acc1[mi][nn] = (f32x4){0.f, 0.f, 0.f, 0.f};
    }

  float GM[32], GH[2];                          // single staging buffer (depth-1)

  // phase k = pass*(5) + row, row 0..4: gy = y0 - 1 + row
  auto LOADP = [&](int k) {
    int gy = y0 + (k % 5) - 1;                  // wave-uniform
    if ((unsigned)gy < (unsigned)HH) {
      const float* ps = x + ((size_t)((b*CIN + (k / 5)*32)*HH + gy))*WW;
      #pragma unroll
      for (int cc = 0; cc < 32; ++cc) GM[cc] = ps[(size_t)cc*HH*WW + gxc];
      GH[0] = ps[(size_t)(2*hp    )*HH*WW + gxhc];
      GH[1] = ps[(size_t)(2*hp + 1)*HH*WW + gxhc];
    }                                           // OOB row: GM/GH unused
  };

  auto WRITEP = [&](int k) {
    int gy = y0 + (k % 5) - 1;
    char* base = lds + (k & 1)*4352;
    if ((unsigned)gy < (unsigned)HH) {
      #pragma unroll
      for (int c = 0; c < 4; ++c) {
        unsigned int pk[4];
        #pragma unroll
        for (int w = 0; w < 4; ++w) {
          pk[w] = cvtpk(GM[c*8 + 2*w], GM[c*8 + 2*w + 1]);
          pk[w] = gxv ? pk[w] : 0u;             // zero-pad cols gx==-1/128/129
        }
        *(u32x4*)(base + stoff[c]) = *(u32x4*)pk;
      }
      unsigned int hw = cvtpk(GH[0], GH[1]);
      hw = gxhv ? hw : 0u;
      if (lane < 48) *(unsigned int*)(base + hoff) = hw;
    } else {                                    // OOB row: zeros (both passes)
      #pragma unroll
      for (int c = 0; c < 4; ++c)
        *(u32x4*)(base + stoff[c]) = (u32x4){0u,0u,0u,0u};
      if (lane < 48) *(unsigned int*)(base + hoff) = 0u;
    }
  };

  // COMPUTE(k): staged row r = k%5 feeds out-row0 with tap-row r (r<4) and
  // out-row1 with tap-row r-1 (r>=1). A-fragments are shared by both.
  auto COMPUTE = [&](int k) {
    const int r = k % 5;
    const char* ab = lds + (k & 1)*4352;
    const char* wb = (const char*)wb2 + (size_t)(k / 5)*65536 + (size_t)lane*16;
    #pragma unroll
    for (int s = 0; s < 4; ++s) {
      bf16x8 afr[4];
      #pragma unroll
      for (int mi = 0; mi < 4; ++mi)
        afr[mi] = *(const bf16x8*)(ab + aoff[s] + mi*1024);
      if (r < 4) {                              // out row 0, rs = r*4+s
        const char* w0 = wb + (size_t)(r*4 + s)*4096;
        bf16x8 b0[4];
        #pragma unroll
        for (int n = 0; n < 4; ++n) b0[n] = *(const bf16x8*)(w0 + n*1024);
        #pragma unroll
        for (int mi = 0; mi < 4; ++mi)
          #pragma unroll
          for (int nn = 0; nn < 4; ++nn)
            acc0[mi][nn] = __builtin_amdgcn_mfma_f32_16x16x32_bf16(afr[mi], b0[nn], acc0[mi][nn], 0, 0, 0);
      }
      if (r >= 1) {                             // out row 1, rs = (r-1)*4+s
        const char* w1 = wb + (size_t)((r-1)*4 + s)*4096;
        bf16x8 b1[4];
        #pragma unroll
        for (int n = 0; n < 4; ++n) b1[n] = *(const bf16x8*)(w1 + n*1024);
        #pragma unroll
        for (int mi = 0; mi < 4; ++mi)
          #pragma unroll
          for (int nn = 0; nn < 4; ++nn)
            acc1[mi][nn] = __builtin_amdgcn_mfma_f32_16x16x32_bf16(afr[mi], b1[nn], acc1[mi][nn], 0, 0, 0);
      }
    }
  };

  // ---- pipeline: WRITE(k) | LOAD(k+1) | COMPUTE(k), 10 phases, no barriers ----
  LOADP(0);
  #pragma unroll
  for (int k = 0; k < 10; ++k) {
    WRITEP(k);                                  // waits on loads(k), covered by COMPUTE(k-1)
    if (k < 9) LOADP(k + 1);                    // issue early; covered by COMPUTE(k)
    COMPUTE(k);
  }

  // ---- epilogue: per out row, transpose through LDS (single wave), store ----
  float* epi = (float*)lds;
  #pragma unroll
  for (int mi = 0; mi < 4; ++mi)
    #pragma unroll
    for (int nn = 0; nn < 4; ++nn) {
      int o  = nn*16 + m15;
      int px = mi*16 + q*4;                     // D row = q*4 + reg
      *(f32x4*)&epi[o*68 + px] = acc0[mi][nn];
    }
  #pragma unroll
  for (int i2 = 0; i2 < 16; ++i2) {
    int o  = i2*4 + q;
    int px = m15*4;
    f32x4 v = *(const f32x4*)&epi[o*68 + px];
    *(f32x4*)&out[(((size_t)(b*COUT + o))*HH + y0)*WW + x0 + px] = v;
  }
  #pragma unroll
  for (int mi = 0; mi < 4; ++mi)
    #pragma unroll
    for (int nn = 0; nn < 4; ++nn) {
      int o  = nn*16 + m15;
      int px = mi*16 + q*4;
      *(f32x4*)&epi[o*68 + px] = acc1[mi][nn];
    }
  #pragma unroll
  for (int i2 = 0; i2 < 16; ++i2) {
    int o  = i2*4 + q;
    int px = m15*4;
    f32x4 v = *(const f32x4*)&epi[o*68 + px];
    *(f32x4*)&out[(((size_t)(b*COUT + o))*HH + (y0 + 1))*WW + x0 + px] = v;
  }
}

// ---------------------------------------------------------------------------
extern "C" void kernel_launch(void* const* d_in, const int* in_sizes, int n_in,
                              void* d_out, int out_size, void* d_ws, size_t ws_size,
                              hipStream_t stream)
{
  const float* x   = (const float*)d_in[0];   // [8,64,128,128] fp32
  const float* wgt = (const float*)d_in[1];   // [64,64,9] fp32
  const float* off = (const float*)d_in[2];   // [9,2] fp32
  float* out = (float*)d_out;                 // [8,64,128,128] fp32
  unsigned short* wb2 = (unsigned short*)d_ws;// 128 KB stream-layout weights

  make_wb<<<64, 64, 0, stream>>>(wgt, off, wb2);
  conv_mfma<<<1024, 64, 0, stream>>>(x, wb2, out);
}

// Round 9
// 107.568 us; speedup vs baseline: 1.4695x; 1.4695x over previous
//
#include <hip/hip_runtime.h>

// B=8, Cin=64, H=W=128, Cout=64, 9 bilinear taps at (i+0.4, j+0.4) == exact 4x4
// conv with zero pad. Implicit GEMM, bf16 MFMA 16x16x32.
//
// v12: 2-row strip with Cout-half blocks (spill-proof wb2 halving).
//   - v11 post-mortem: acc128 + dual-row frags + GM spilled (~50 MB scratch
//     traffic, FETCH 42.6/WRITE 60.8); 1024 blocks = 1 wave/SIMD killed TLP.
//   - wb2 L2 bytes per out-region depend only on (rows x px) per wave, NOT on
//     the Cout split -> strip = 2 rows x 64 px x 32 Cout keeps the full 2x
//     wb2 reduction with acc = 64 VGPRs. Single wave, barrier-free v10 ring.
//   - 2048 blocks = 8 blocks/CU = 2 waves/SIMD (v10's TLP). VGPR ~160: safe.
//   - Traffic/out-px: wb2 2048->1024 B, x 1088->1360 B, out 256
//     => 3.39 -> 2.64 KB/px (~-22% L2) => ~10 us conv floor.
//   - Same (pass asc, rs asc, K=32 grouping) accumulation order per output
//     element -> bitwise-identical output.

#define CIN   64
#define COUT  64
#define HH    128
#define WW    128

typedef __attribute__((ext_vector_type(8))) short bf16x8;   // 8 bf16 = 4 VGPRs
typedef __attribute__((ext_vector_type(4))) float f32x4;
typedef __attribute__((ext_vector_type(4))) unsigned int u32x4;

__device__ __forceinline__ unsigned short f2bf(float f) {
  unsigned int u = __float_as_uint(f);
  u = (u + 0x7fffu + ((u >> 16) & 1u)) >> 16;   // RNE
  return (unsigned short)u;
}

__device__ __forceinline__ unsigned int cvtpk(float lo, float hi) {
  unsigned int r;                                // D = {bf16(lo), bf16(hi)} RNE
  asm("v_cvt_pk_bf16_f32 %0, %1, %2" : "=v"(r) : "v"(lo), "v"(hi));
  return r;
}

// ---------------------------------------------------------------------------
// W4[o][c][r][s] = sum_k w[o,c,k] * cy_k(r-iy_k) * cx_k(s-ix_k).
// Stream layout: wb2[(((p*16+rs)*4 + n)*64 + lane)*8 + j]; consuming lane l
// holds o = n*16 + (l&15), ch = p*32 + (l>>4)*8 + j, for tap rs. (verified)
// ---------------------------------------------------------------------------
__global__ void make_wb(const float* __restrict__ wgt,
                        const float* __restrict__ off,
                        unsigned short* __restrict__ wb2)
{
  int id = blockIdx.x * 64 + threadIdx.x;       // 4096 = 64*64
  int o = id >> 6, c = id & 63;
  float W16[16];
  #pragma unroll
  for (int i = 0; i < 16; ++i) W16[i] = 0.f;
  for (int k = 0; k < 9; ++k) {
    float dy = off[2*k], dx = off[2*k+1];
    float fyf = floorf(dy), fxf = floorf(dx);
    int   iy = (int)fyf,   ix = (int)fxf;       // in {0,1,2}
    float fy = dy - fyf,   fx = dx - fxf;
    float wk = wgt[(o*CIN + c)*9 + k];
    W16[(iy  )*4 + ix  ] += wk * (1.f-fy)*(1.f-fx);
    W16[(iy  )*4 + ix+1] += wk * (1.f-fy)*fx;
    W16[(iy+1)*4 + ix  ] += wk * fy*(1.f-fx);
    W16[(iy+1)*4 + ix+1] += wk * fy*fx;
  }
  int p = c >> 5, q = (c >> 3) & 3, j = c & 7;
  int n = o >> 4, m15 = o & 15;
  int lanei = q*16 + m15;
  for (int rs = 0; rs < 16; ++rs)
    wb2[(size_t)(((p*16 + rs)*4 + n)*64 + lanei)*8 + j] = f2bf(W16[rs]);
}

// ---------------------------------------------------------------------------
// conv: 1 wave per block, strip = 2 out rows x 64 px x 32 Cout, no barriers.
// LDS ring: slot(k&1) = 68 cols x 4 chunk-slots x 16 B = 4352 B, XOR swizzle.
// ---------------------------------------------------------------------------
__global__ __launch_bounds__(64, 2)   // VGPR cap 256 (est ~160 used)
void conv_mfma(const float* __restrict__ x,
               const unsigned short* __restrict__ wb2,
               float* __restrict__ out)
{
  __shared__ __align__(16) char lds[17408];     // ring 2x4352 B; epi f32[32][68]

  const int wg  = blockIdx.x;                   // 2048
  const int xcd = wg & 7;
  const int i   = wg >> 3;                      // 0..255
  const int b   = i >> 5;                       // 0..7
  const int r5  = i & 31;
  const int y0  = xcd * 16 + (r5 >> 2) * 2;     // first out row of the pair
  const int x0  = ((r5 >> 1) & 1) * 64;         // x half
  const int coh = r5 & 1;                       // Cout half
  const int lane = threadIdx.x;                 // 0..63
  const int m15  = lane & 15;
  const int q    = lane >> 4;

  // ---- per-lane staging constants (same as v10) ----
  int gx   = x0 - 1 + lane;                     // main col = lane
  bool gxv = ((unsigned)gx < (unsigned)WW);
  int gxc  = gx < 0 ? 0 : (gx > WW-1 ? WW-1 : gx);
  const int he = (lane >> 4) < 3 ? (lane >> 4) : 2;   // halo col 64+he
  int gxh  = x0 + 63 + he;
  bool gxhv = ((unsigned)gxh < (unsigned)WW) && (lane < 48);
  int gxhc = gxh > WW-1 ? WW-1 : gxh;
  const int hp = lane & 15;                     // halo ch-pair: ch = 2hp, 2hp+1
  const int hoff = (64 + he)*64 + ((hp >> 2) & 3)*16 + (hp & 3)*4;

  int stoff[4];
  #pragma unroll
  for (int c = 0; c < 4; ++c)
    stoff[c] = lane*64 + ((c + (lane >> 2)) & 3)*16;

  int aoff[4];
  #pragma unroll
  for (int s = 0; s < 4; ++s) {
    int c0 = m15 + s;
    aoff[s] = c0*64 + ((q + (c0 >> 2)) & 3)*16;
  }

  f32x4 acc0[4][2], acc1[4][2];
  #pragma unroll
  for (int mi = 0; mi < 4; ++mi)
    #pragma unroll
    for (int nn = 0; nn < 2; ++nn) {
      acc0[mi][nn] = (f32x4){0.f, 0.f, 0.f, 0.f};
      acc1[mi][nn] = (f32x4){0.f, 0.f, 0.f, 0.f};
    }

  float GM[32], GH[2];                          // depth-1 staging buffer

  // phase k = pass*5 + row, row 0..4: gy = y0 - 1 + row
  auto LOADP = [&](int k) {
    int gy = y0 + (k % 5) - 1;                  // wave-uniform
    if ((unsigned)gy < (unsigned)HH) {
      const float* ps = x + ((size_t)((b*CIN + (k / 5)*32)*HH + gy))*WW;
      #pragma unroll
      for (int cc = 0; cc < 32; ++cc) GM[cc] = ps[(size_t)cc*HH*WW + gxc];
      GH[0] = ps[(size_t)(2*hp    )*HH*WW + gxhc];
      GH[1] = ps[(size_t)(2*hp + 1)*HH*WW + gxhc];
    }                                           // OOB row: GM/GH unused
  };

  auto WRITEP = [&](int k) {
    int gy = y0 + (k % 5) - 1;
    char* base = lds + (k & 1)*4352;
    if ((unsigned)gy < (unsigned)HH) {
      #pragma unroll
      for (int c = 0; c < 4; ++c) {
        unsigned int pk[4];
        #pragma unroll
        for (int w = 0; w < 4; ++w) {
          pk[w] = cvtpk(GM[c*8 + 2*w], GM[c*8 + 2*w + 1]);
          pk[w] = gxv ? pk[w] : 0u;             // zero-pad cols gx==-1/128/129
        }
        *(u32x4*)(base + stoff[c]) = *(u32x4*)pk;
      }
      unsigned int hw = cvtpk(GH[0], GH[1]);
      hw = gxhv ? hw : 0u;
      if (lane < 48) *(unsigned int*)(base + hoff) = hw;
    } else {                                    // OOB row: zeros (both passes)
      #pragma unroll
      for (int c = 0; c < 4; ++c)
        *(u32x4*)(base + stoff[c]) = (u32x4){0u,0u,0u,0u};
      if (lane < 48) *(unsigned int*)(base + hoff) = 0u;
    }
  };

  // COMPUTE(k): staged row r = k%5 feeds out-row0 with tap-row r (r<4) and
  // out-row1 with tap-row r-1 (r>=1). A-fragments shared by both rows.
  auto COMPUTE = [&](int k) {
    const int r = k % 5;
    const char* ab = lds + (k & 1)*4352;
    const char* wb = (const char*)wb2 + (size_t)(k / 5)*65536 + coh*2048
                     + (size_t)lane*16;
    #pragma unroll
    for (int s = 0; s < 4; ++s) {
      bf16x8 afr[4];
      #pragma unroll
      for (int mi = 0; mi < 4; ++mi)
        afr[mi] = *(const bf16x8*)(ab + aoff[s] + mi*1024);
      if (r < 4) {                              // out row 0, rs = r*4+s
        const char* w0 = wb + (size_t)(r*4 + s)*4096;
        bf16x8 b0[2];
        #pragma unroll
        for (int nn = 0; nn < 2; ++nn) b0[nn] = *(const bf16x8*)(w0 + nn*1024);
        #pragma unroll
        for (int mi = 0; mi < 4; ++mi)
          #pragma unroll
          for (int nn = 0; nn < 2; ++nn)
            acc0[mi][nn] = __builtin_amdgcn_mfma_f32_16x16x32_bf16(afr[mi], b0[nn], acc0[mi][nn], 0, 0, 0);
      }
      if (r >= 1) {                             // out row 1, rs = (r-1)*4+s
        const char* w1 = wb + (size_t)((r-1)*4 + s)*4096;
        bf16x8 b1[2];
        #pragma unroll
        for (int nn = 0; nn < 2; ++nn) b1[nn] = *(const bf16x8*)(w1 + nn*1024);
        #pragma unroll
        for (int mi = 0; mi < 4; ++mi)
          #pragma unroll
          for (int nn = 0; nn < 2; ++nn)
            acc1[mi][nn] = __builtin_amdgcn_mfma_f32_16x16x32_bf16(afr[mi], b1[nn], acc1[mi][nn], 0, 0, 0);
      }
    }
  };

  // ---- pipeline: WRITE(k) | LOAD(k+1) | COMPUTE(k), 10 phases, no barriers ----
  LOADP(0);
  #pragma unroll
  for (int k = 0; k < 10; ++k) {
    WRITEP(k);                                  // GM(k) -> LDS (WAR frees GM)
    if (k < 9) LOADP(k + 1);                    // in flight across COMPUTE(k)
    COMPUTE(k);
  }

  // ---- epilogue: per out row, transpose through LDS (single wave), store ----
  float* epi = (float*)lds;                     // [32 o][68 px] f32 = 8704 B
  #pragma unroll
  for (int mi = 0; mi < 4; ++mi)
    #pragma unroll
    for (int nn = 0; nn < 2; ++nn) {
      int o  = nn*16 + m15;                     // o within the Cout half
      int px = mi*16 + q*4;                     // D row = q*4 + reg
      *(f32x4*)&epi[o*68 + px] = acc0[mi][nn];
    }
  #pragma unroll
  for (int i2 = 0; i2 < 8; ++i2) {
    int o  = i2*4 + q;
    int px = m15*4;
    f32x4 v = *(const f32x4*)&epi[o*68 + px];
    *(f32x4*)&out[(((size_t)(b*COUT + coh*32 + o))*HH + y0)*WW + x0 + px] = v;
  }
  #pragma unroll
  for (int mi = 0; mi < 4; ++mi)
    #pragma unroll
    for (int nn = 0; nn < 2; ++nn) {
      int o  = nn*16 + m15;
      int px = mi*16 + q*4;
      *(f32x4*)&epi[o*68 + px] = acc1[mi][nn];
    }
  #pragma unroll
  for (int i2 = 0; i2 < 8; ++i2) {
    int o  = i2*4 + q;
    int px = m15*4;
    f32x4 v = *(const f32x4*)&epi[o*68 + px];
    *(f32x4*)&out[(((size_t)(b*COUT + coh*32 + o))*HH + (y0 + 1))*WW + x0 + px] = v;
  }
}

// ---------------------------------------------------------------------------
extern "C" void kernel_launch(void* const* d_in, const int* in_sizes, int n_in,
                              void* d_out, int out_size, void* d_ws, size_t ws_size,
                              hipStream_t stream)
{
  const float* x   = (const float*)d_in[0];   // [8,64,128,128] fp32
  const float* wgt = (const float*)d_in[1];   // [64,64,9] fp32
  const float* off = (const float*)d_in[2];   // [9,2] fp32
  float* out = (float*)d_out;                 // [8,64,128,128] fp32
  unsigned short* wb2 = (unsigned short*)d_ws;// 128 KB stream-layout weights

  make_wb<<<64, 64, 0, stream>>>(wgt, off, wb2);
  conv_mfma<<<2048, 64, 0, stream>>>(x, wb2, out);
}